// Round 5
// baseline (321.198 us; speedup 1.0000x reference)
//
#include <hip/hip_runtime.h>

// Decorrelation (iterative whitening) normalization.
// Input:  (64, 56, 56, 256) f32, NHWC (C contiguous). N = 200704 positions.
// Groups: 16 groups x 16 channels. Newton-Schulz x5 for Sigma^{-1/2}.
//
// Lane mapping (streaming kernels): lane handles channels [4*lane, 4*lane+4)
// => quad (4 consecutive lanes) == one 16-channel group. Cross-channel products
// within the group use DPP quad_perm broadcasts (VALU, no LDS pipe).
//
// k_stats is latency-bound: the fix (round 5) is occupancy, not per-wave
// pipelining. 2048 blocks (32 waves/CU static) with a low-VGPR depth-1
// prefetch loop -- the exact structure k_whiten uses to move 410 MB in 50 us.
//
// ws float layout:
//   [0,    256)   : final channel sums (zeroed, k_reduce atomics)
//   [256,  4352)  : final cov sums (g*256 + i*16 + j)
//   [4352, 4608)  : channel means (written by k_wm)
//   [4608, 8704)  : whitening matrices (g*256 + i*16 + j)
//   [8704, ...)   : per-block partials, nblk x 4352 (plain coalesced stores)

constexpr int CCH = 256;
constexpr float EPSV = 1e-3f;
constexpr int PSTRIDE = 4352;   // floats per partial record
constexpr int MAXBLK = 2048;    // preferred k_stats block count

// DPP quad_perm broadcast of lane (quad_base + S) within each 4-lane quad.
#define QB(S, comp) __int_as_float(__builtin_amdgcn_update_dpp( \
    0, __float_as_int(comp), (S) * 0x55, 0xF, 0xF, 1))

// Swizzled LDS cov index: <=2-way bank conflicts for the wave-wide atomics.
__device__ __forceinline__ int cidx(int g, int i, int j) {
    return g * 273 + i * 17 + j;
}

__global__ __launch_bounds__(256) void k_stats(const float* __restrict__ x,
                                               float* __restrict__ partial,
                                               int npos) {
    const int tid = threadIdx.x;
    const int lane = tid & 63;
    const int wave = blockIdx.x * (blockDim.x >> 6) + (tid >> 6);
    const int nwaves = gridDim.x * (blockDim.x >> 6);

    float s4[4] = {0.f, 0.f, 0.f, 0.f};
    float cv[4][16];
#pragma unroll
    for (int a = 0; a < 4; ++a)
#pragma unroll
        for (int j = 0; j < 16; ++j) cv[a][j] = 0.f;

    const float* bx = x + lane * 4;

    int p = wave;
    if (p < npos) {
        float4 v = *reinterpret_cast<const float4*>(bx + (size_t)p * CCH);
        while (true) {
            const int pn = p + nwaves;
            const bool more = pn < npos;
            float4 vn = v;
            if (more) vn = *reinterpret_cast<const float4*>(bx + (size_t)pn * CCH);

            s4[0] += v.x; s4[1] += v.y; s4[2] += v.z; s4[3] += v.w;
            const float va[4] = {v.x, v.y, v.z, v.w};
#define STEP(S)                                                          \
            {                                                            \
                const float u0 = QB(S, v.x), u1 = QB(S, v.y),            \
                            u2 = QB(S, v.z), u3 = QB(S, v.w);            \
                _Pragma("unroll")                                        \
                for (int a = 0; a < 4; ++a) {                            \
                    cv[a][(S) * 4 + 0] += va[a] * u0;                    \
                    cv[a][(S) * 4 + 1] += va[a] * u1;                    \
                    cv[a][(S) * 4 + 2] += va[a] * u2;                    \
                    cv[a][(S) * 4 + 3] += va[a] * u3;                    \
                }                                                        \
            }
            STEP(0) STEP(1) STEP(2) STEP(3)
#undef STEP
            if (!more) break;
            p = pn;
            v = vn;
        }
    }

    // Block-level merge (swizzled LDS to avoid 64-way bank conflicts).
    __shared__ float lsum[324];    // lane*5 + a
    __shared__ float lcov[4368];   // cidx(g, i, j)
    for (int i2 = tid; i2 < 324; i2 += blockDim.x) lsum[i2] = 0.f;
    for (int i2 = tid; i2 < 4368; i2 += blockDim.x) lcov[i2] = 0.f;
    __syncthreads();

    const int g = lane >> 2;
    const int il0 = (lane & 3) * 4;
#pragma unroll
    for (int a = 0; a < 4; ++a) atomicAdd(&lsum[lane * 5 + a], s4[a]);
#pragma unroll
    for (int a = 0; a < 4; ++a)
#pragma unroll
        for (int j = 0; j < 16; ++j)
            atomicAdd(&lcov[cidx(g, il0 + a, j)], cv[a][j]);
    __syncthreads();

    // Plain coalesced stores of this block's partial record (no atomics).
    float* rec = partial + (size_t)blockIdx.x * PSTRIDE;
    for (int c = tid; c < 256; c += blockDim.x)
        rec[c] = lsum[(c >> 2) * 5 + (c & 3)];
    for (int e = tid; e < 4096; e += blockDim.x) {
        const int gg = e >> 8, r = e & 255;
        rec[256 + e] = lcov[cidx(gg, r >> 4, r & 15)];
    }
}

// Reduce nblk partial records into the final 4352 accumulators.
// Thread t handles element e of a 64-record chunk; <=ceil(nblk/64)
// atomics per address. Consecutive threads read consecutive floats.
__global__ __launch_bounds__(256) void k_reduce(const float* __restrict__ partial,
                                                float* __restrict__ finalv,
                                                int nblk, int nchunks) {
    const int t = blockIdx.x * blockDim.x + threadIdx.x;
    const int total = nchunks * PSTRIDE;
    if (t >= total) return;
    const int chunk = t / PSTRIDE;
    const int e = t - chunk * PSTRIDE;
    const int r0 = chunk * 64;
    const int rend = (r0 + 64 < nblk) ? r0 + 64 : nblk;
    const float* src = partial + (size_t)r0 * PSTRIDE + e;
    float acc = 0.f;
    for (int r = r0; r < rend; ++r, src += PSTRIDE) acc += *src;
    atomicAdd(&finalv[e], acc);
}

// One block per group; thread (i,j) owns element (i,j) of the 16x16 matrices.
__global__ __launch_bounds__(256) void k_wm(const float* __restrict__ sums,
                                            const float* __restrict__ covs,
                                            float* __restrict__ mean,
                                            float* __restrict__ wm,
                                            float inv_n) {
    const int g = blockIdx.x;
    const int tid = threadIdx.x;
    const int i = tid >> 4;
    const int j = tid & 15;

    __shared__ float mu[16];
    __shared__ float sig[16][17];
    __shared__ float P[16][17];
    __shared__ float T[16][17];
    __shared__ float U[16][17];

    if (tid < 16) {
        float m = sums[g * 16 + tid] * inv_n;
        mu[tid] = m;
        mean[g * 16 + tid] = m;
    }
    __syncthreads();

    const float cov = covs[(g * 16 + i) * 16 + j] * inv_n - mu[i] * mu[j];
    const float s = (1.0f - EPSV) * cov + ((i == j) ? EPSV : 0.0f);
    sig[i][j] = s;
    __syncthreads();

    float tr = 0.f;
#pragma unroll
    for (int k = 0; k < 16; ++k) tr += sig[k][k];
    __syncthreads();

    sig[i][j] = s / tr;               // sigma_n
    P[i][j] = (i == j) ? 1.0f : 0.0f;
    __syncthreads();

    for (int it = 0; it < 5; ++it) {
        float a = 0.f;
#pragma unroll
        for (int k = 0; k < 16; ++k) a += P[i][k] * P[k][j];
        T[i][j] = a;
        __syncthreads();

        float b = 0.f;
#pragma unroll
        for (int k = 0; k < 16; ++k) b += T[i][k] * P[k][j];
        U[i][j] = b;
        __syncthreads();

        float c = 0.f;
#pragma unroll
        for (int k = 0; k < 16; ++k) c += U[i][k] * sig[k][j];
        const float pn = 1.5f * P[i][j] - 0.5f * c;
        __syncthreads();
        P[i][j] = pn;
        __syncthreads();
    }

    wm[(g * 16 + i) * 16 + j] = P[i][j] * rsqrtf(tr);
}

__global__ __launch_bounds__(256) void k_whiten(const float* __restrict__ x,
                                                const float* __restrict__ mean,
                                                const float* __restrict__ wm,
                                                float* __restrict__ out,
                                                int npos) {
    const int tid = threadIdx.x;
    const int lane = tid & 63;
    const int wave = blockIdx.x * (blockDim.x >> 6) + (tid >> 6);
    const int nwaves = gridDim.x * (blockDim.x >> 6);
    const int g = lane >> 2;
    const int i0 = (lane & 3) * 4;

    // Per-lane whitening rows: 4 output channels x 16 input channels.
    float w[4][16];
    const float* wg = wm + g * 256;
#pragma unroll
    for (int a = 0; a < 4; ++a)
#pragma unroll
        for (int j = 0; j < 16; ++j) w[a][j] = wg[(i0 + a) * 16 + j];

    const float4 mu4 = *reinterpret_cast<const float4*>(mean + lane * 4);
    const float* bx = x + lane * 4;
    float* bo = out + lane * 4;

    int p = wave;
    if (p >= npos) return;
    float4 v = *reinterpret_cast<const float4*>(bx + (size_t)p * CCH);
    while (true) {
        const int pn = p + nwaves;
        const bool more = pn < npos;
        float4 vn = v;
        if (more) vn = *reinterpret_cast<const float4*>(bx + (size_t)pn * CCH);

        v.x -= mu4.x; v.y -= mu4.y; v.z -= mu4.z; v.w -= mu4.w;
        float acc[4] = {0.f, 0.f, 0.f, 0.f};
#define WSTEP(S)                                                         \
        {                                                                \
            const float u0 = QB(S, v.x), u1 = QB(S, v.y),                \
                        u2 = QB(S, v.z), u3 = QB(S, v.w);                \
            _Pragma("unroll")                                            \
            for (int a = 0; a < 4; ++a) {                                \
                acc[a] += w[a][(S) * 4 + 0] * u0 + w[a][(S) * 4 + 1] * u1 \
                        + w[a][(S) * 4 + 2] * u2 + w[a][(S) * 4 + 3] * u3; \
            }                                                            \
        }
        WSTEP(0) WSTEP(1) WSTEP(2) WSTEP(3)
#undef WSTEP
        float4 o;
        o.x = acc[0]; o.y = acc[1]; o.z = acc[2]; o.w = acc[3];
        *reinterpret_cast<float4*>(bo + (size_t)p * CCH) = o;

        if (!more) break;
        p = pn;
        v = vn;
    }
}

extern "C" void kernel_launch(void* const* d_in, const int* in_sizes, int n_in,
                              void* d_out, int out_size, void* d_ws, size_t ws_size,
                              hipStream_t stream) {
    const float* x = (const float*)d_in[0];
    float* out = (float*)d_out;
    float* ws = (float*)d_ws;

    const int total = in_sizes[0];
    const int npos = total / CCH;   // 200704
    const float inv_n = 1.0f / (float)npos;

    float* finalv = ws;            // [0,4352): sums+covs
    float* mean = ws + 4352;
    float* wm = ws + 4608;
    float* partial = ws + 8704;    // nblk * PSTRIDE floats

    // As many stat blocks as scratch allows (occupancy is the lever).
    long avail = (long)(ws_size / 4) - 8704;
    int nblk = (int)(avail / PSTRIDE);
    if (nblk > MAXBLK) nblk = MAXBLK;
    if (nblk < 64) nblk = 64;   // ws is always big enough for this in practice

    // zero only the final accumulators (k_reduce atomics land here)
    hipMemsetAsync(d_ws, 0, 4352 * sizeof(float), stream);

    k_stats<<<nblk, 256, 0, stream>>>(x, partial, npos);
    const int nchunks = (nblk + 63) / 64;
    const int rthreads = nchunks * PSTRIDE;
    k_reduce<<<(rthreads + 255) / 256, 256, 0, stream>>>(partial, finalv, nblk, nchunks);
    k_wm<<<16, 256, 0, stream>>>(finalv, finalv + 256, mean, wm, inv_n);
    k_whiten<<<2048, 256, 0, stream>>>(x, mean, wm, out, npos);
}

// Round 6
// 238.293 us; speedup vs baseline: 1.3479x; 1.3479x over previous
//
#include <hip/hip_runtime.h>

// Decorrelation (iterative whitening) normalization.
// Input:  (64, 56, 56, 256) f32, NHWC (C contiguous). N = 200704 positions.
// Groups: 16 groups x 16 channels. Newton-Schulz x5 for Sigma^{-1/2}.
//
// Lane mapping (streaming kernels): lane handles channels [4*lane, 4*lane+4)
// => quad (4 consecutive lanes) == one 16-channel group. Cross-channel products
// within the group use DPP quad_perm broadcasts (VALU, no LDS pipe).
//
// Round-6 fix: k_stats's 64 covariance accumulators were being demoted out of
// arch VGPRs (VGPR_Count=44 < 64 live floats => scratch/AGPR round-trips on
// every FMA; explains low VALUBusy + anti-scaling with wave count). Force
// register residency with 16 NAMED float4 accumulators + launch_bounds(256,4).
//
// ws float layout:
//   [0,    256)   : final channel sums (zeroed, k_reduce atomics)
//   [256,  4352)  : final cov sums (g*256 + i*16 + j)
//   [4352, 4608)  : channel means (written by k_wm)
//   [4608, 8704)  : whitening matrices (g*256 + i*16 + j)
//   [8704, ...)   : per-block partials, nblk x 4352 (plain coalesced stores)

constexpr int CCH = 256;
constexpr float EPSV = 1e-3f;
constexpr int PSTRIDE = 4352;   // floats per partial record
constexpr int STATBLK = 1024;   // k_stats blocks: 4096 waves, 49 iters exact

// DPP quad_perm broadcast of lane (quad_base + S) within each 4-lane quad.
#define QB(S, comp) __int_as_float(__builtin_amdgcn_update_dpp( \
    0, __float_as_int(comp), (S) * 0x55, 0xF, 0xF, 1))

// Swizzled LDS cov index: <=2-way bank conflicts for the wave-wide atomics.
__device__ __forceinline__ int cidx(int g, int i, int j) {
    return g * 273 + i * 17 + j;
}

// c_{4S+t}.a += v.a * u_t  where u_t = QB(S, v component t).
#define FMA4(C, V, U) \
    { C.x += (V).x * (U); C.y += (V).y * (U); C.z += (V).z * (U); C.w += (V).w * (U); }

#define QUAD(S, CA, CB, CC, CD, V)                                        \
    {                                                                     \
        const float u0 = QB(S, (V).x), u1 = QB(S, (V).y),                 \
                    u2 = QB(S, (V).z), u3 = QB(S, (V).w);                 \
        FMA4(CA, V, u0) FMA4(CB, V, u1) FMA4(CC, V, u2) FMA4(CD, V, u3)   \
    }

#define ACCPOS(V)                                                         \
    {                                                                     \
        ss.x += (V).x; ss.y += (V).y; ss.z += (V).z; ss.w += (V).w;       \
        QUAD(0, c0, c1, c2, c3, V)                                        \
        QUAD(1, c4, c5, c6, c7, V)                                        \
        QUAD(2, c8, c9, c10, c11, V)                                      \
        QUAD(3, c12, c13, c14, c15, V)                                    \
    }

__global__ __launch_bounds__(256, 4) void k_stats(const float* __restrict__ x,
                                                  float* __restrict__ partial,
                                                  int npos) {
    const int tid = threadIdx.x;
    const int lane = tid & 63;
    const int wave = blockIdx.x * (blockDim.x >> 6) + (tid >> 6);
    const int nwaves = gridDim.x * (blockDim.x >> 6);

    float4 ss = {0.f, 0.f, 0.f, 0.f};
    float4 c0 = ss, c1 = ss, c2 = ss, c3 = ss, c4 = ss, c5 = ss, c6 = ss,
           c7 = ss, c8 = ss, c9 = ss, c10 = ss, c11 = ss, c12 = ss, c13 = ss,
           c14 = ss, c15 = ss;

    const float* bx = x + lane * 4;

    int p = wave;
    if (p < npos) {
        float4 v = *reinterpret_cast<const float4*>(bx + (size_t)p * CCH);
        while (true) {
            const int pn = p + nwaves;
            const bool more = pn < npos;
            float4 vn = v;
            if (more) vn = *reinterpret_cast<const float4*>(bx + (size_t)pn * CCH);
            ACCPOS(v);
            if (!more) break;
            p = pn;
            v = vn;
        }
    }

    // Block-level merge (swizzled LDS to avoid 64-way bank conflicts).
    __shared__ float lsum[324];    // lane*5 + a
    __shared__ float lcov[4368];   // cidx(g, i, j)
    for (int i2 = tid; i2 < 324; i2 += blockDim.x) lsum[i2] = 0.f;
    for (int i2 = tid; i2 < 4368; i2 += blockDim.x) lcov[i2] = 0.f;
    __syncthreads();

    const int g = lane >> 2;
    const int i0 = (lane & 3) * 4;
    atomicAdd(&lsum[lane * 5 + 0], ss.x);
    atomicAdd(&lsum[lane * 5 + 1], ss.y);
    atomicAdd(&lsum[lane * 5 + 2], ss.z);
    atomicAdd(&lsum[lane * 5 + 3], ss.w);
#define MRG(J, C)                                     \
    atomicAdd(&lcov[cidx(g, i0 + 0, J)], (C).x);      \
    atomicAdd(&lcov[cidx(g, i0 + 1, J)], (C).y);      \
    atomicAdd(&lcov[cidx(g, i0 + 2, J)], (C).z);      \
    atomicAdd(&lcov[cidx(g, i0 + 3, J)], (C).w);
    MRG(0, c0)  MRG(1, c1)  MRG(2, c2)  MRG(3, c3)
    MRG(4, c4)  MRG(5, c5)  MRG(6, c6)  MRG(7, c7)
    MRG(8, c8)  MRG(9, c9)  MRG(10, c10) MRG(11, c11)
    MRG(12, c12) MRG(13, c13) MRG(14, c14) MRG(15, c15)
#undef MRG
    __syncthreads();

    // Plain coalesced stores of this block's partial record (no atomics).
    float* rec = partial + (size_t)blockIdx.x * PSTRIDE;
    for (int c = tid; c < 256; c += blockDim.x)
        rec[c] = lsum[(c >> 2) * 5 + (c & 3)];
    for (int e = tid; e < 4096; e += blockDim.x) {
        const int gg = e >> 8, r = e & 255;
        rec[256 + e] = lcov[cidx(gg, r >> 4, r & 15)];
    }
}

// Reduce nblk partial records into the final 4352 accumulators.
// Thread t handles element e of a 64-record chunk; <=ceil(nblk/64)
// atomics per address. Consecutive threads read consecutive floats.
__global__ __launch_bounds__(256) void k_reduce(const float* __restrict__ partial,
                                                float* __restrict__ finalv,
                                                int nblk, int nchunks) {
    const int t = blockIdx.x * blockDim.x + threadIdx.x;
    const int total = nchunks * PSTRIDE;
    if (t >= total) return;
    const int chunk = t / PSTRIDE;
    const int e = t - chunk * PSTRIDE;
    const int r0 = chunk * 64;
    const int rend = (r0 + 64 < nblk) ? r0 + 64 : nblk;
    const float* src = partial + (size_t)r0 * PSTRIDE + e;
    float acc = 0.f;
    for (int r = r0; r < rend; ++r, src += PSTRIDE) acc += *src;
    atomicAdd(&finalv[e], acc);
}

// One block per group; thread (i,j) owns element (i,j) of the 16x16 matrices.
__global__ __launch_bounds__(256) void k_wm(const float* __restrict__ sums,
                                            const float* __restrict__ covs,
                                            float* __restrict__ mean,
                                            float* __restrict__ wm,
                                            float inv_n) {
    const int g = blockIdx.x;
    const int tid = threadIdx.x;
    const int i = tid >> 4;
    const int j = tid & 15;

    __shared__ float mu[16];
    __shared__ float sig[16][17];
    __shared__ float P[16][17];
    __shared__ float T[16][17];
    __shared__ float U[16][17];

    if (tid < 16) {
        float m = sums[g * 16 + tid] * inv_n;
        mu[tid] = m;
        mean[g * 16 + tid] = m;
    }
    __syncthreads();

    const float cov = covs[(g * 16 + i) * 16 + j] * inv_n - mu[i] * mu[j];
    const float s = (1.0f - EPSV) * cov + ((i == j) ? EPSV : 0.0f);
    sig[i][j] = s;
    __syncthreads();

    float tr = 0.f;
#pragma unroll
    for (int k = 0; k < 16; ++k) tr += sig[k][k];
    __syncthreads();

    sig[i][j] = s / tr;               // sigma_n
    P[i][j] = (i == j) ? 1.0f : 0.0f;
    __syncthreads();

    for (int it = 0; it < 5; ++it) {
        float a = 0.f;
#pragma unroll
        for (int k = 0; k < 16; ++k) a += P[i][k] * P[k][j];
        T[i][j] = a;
        __syncthreads();

        float b = 0.f;
#pragma unroll
        for (int k = 0; k < 16; ++k) b += T[i][k] * P[k][j];
        U[i][j] = b;
        __syncthreads();

        float c = 0.f;
#pragma unroll
        for (int k = 0; k < 16; ++k) c += U[i][k] * sig[k][j];
        const float pn = 1.5f * P[i][j] - 0.5f * c;
        __syncthreads();
        P[i][j] = pn;
        __syncthreads();
    }

    wm[(g * 16 + i) * 16 + j] = P[i][j] * rsqrtf(tr);
}

__global__ __launch_bounds__(256) void k_whiten(const float* __restrict__ x,
                                                const float* __restrict__ mean,
                                                const float* __restrict__ wm,
                                                float* __restrict__ out,
                                                int npos) {
    const int tid = threadIdx.x;
    const int lane = tid & 63;
    const int wave = blockIdx.x * (blockDim.x >> 6) + (tid >> 6);
    const int nwaves = gridDim.x * (blockDim.x >> 6);
    const int g = lane >> 2;
    const int i0 = (lane & 3) * 4;

    // Per-lane whitening rows: 4 output channels x 16 input channels.
    float w[4][16];
    const float* wg = wm + g * 256;
#pragma unroll
    for (int a = 0; a < 4; ++a)
#pragma unroll
        for (int j = 0; j < 16; ++j) w[a][j] = wg[(i0 + a) * 16 + j];

    const float4 mu4 = *reinterpret_cast<const float4*>(mean + lane * 4);
    const float* bx = x + lane * 4;
    float* bo = out + lane * 4;

    int p = wave;
    if (p >= npos) return;
    float4 v = *reinterpret_cast<const float4*>(bx + (size_t)p * CCH);
    while (true) {
        const int pn = p + nwaves;
        const bool more = pn < npos;
        float4 vn = v;
        if (more) vn = *reinterpret_cast<const float4*>(bx + (size_t)pn * CCH);

        v.x -= mu4.x; v.y -= mu4.y; v.z -= mu4.z; v.w -= mu4.w;
        float acc[4] = {0.f, 0.f, 0.f, 0.f};
#define WSTEP(S)                                                         \
        {                                                                \
            const float u0 = QB(S, v.x), u1 = QB(S, v.y),                \
                        u2 = QB(S, v.z), u3 = QB(S, v.w);                \
            _Pragma("unroll")                                            \
            for (int a = 0; a < 4; ++a) {                                \
                acc[a] += w[a][(S) * 4 + 0] * u0 + w[a][(S) * 4 + 1] * u1 \
                        + w[a][(S) * 4 + 2] * u2 + w[a][(S) * 4 + 3] * u3; \
            }                                                            \
        }
        WSTEP(0) WSTEP(1) WSTEP(2) WSTEP(3)
#undef WSTEP
        float4 o;
        o.x = acc[0]; o.y = acc[1]; o.z = acc[2]; o.w = acc[3];
        *reinterpret_cast<float4*>(bo + (size_t)p * CCH) = o;

        if (!more) break;
        p = pn;
        v = vn;
    }
}

extern "C" void kernel_launch(void* const* d_in, const int* in_sizes, int n_in,
                              void* d_out, int out_size, void* d_ws, size_t ws_size,
                              hipStream_t stream) {
    const float* x = (const float*)d_in[0];
    float* out = (float*)d_out;
    float* ws = (float*)d_ws;

    const int total = in_sizes[0];
    const int npos = total / CCH;   // 200704
    const float inv_n = 1.0f / (float)npos;

    float* finalv = ws;            // [0,4352): sums+covs
    float* mean = ws + 4352;
    float* wm = ws + 4608;
    float* partial = ws + 8704;    // nblk * PSTRIDE floats

    long avail = (long)(ws_size / 4) - 8704;
    int nblk = (int)(avail / PSTRIDE);
    if (nblk > STATBLK) nblk = STATBLK;
    if (nblk < 64) nblk = 64;   // ws is always big enough for this in practice

    // zero only the final accumulators (k_reduce atomics land here)
    hipMemsetAsync(d_ws, 0, 4352 * sizeof(float), stream);

    k_stats<<<nblk, 256, 0, stream>>>(x, partial, npos);
    const int nchunks = (nblk + 63) / 64;
    const int rthreads = nchunks * PSTRIDE;
    k_reduce<<<(rthreads + 255) / 256, 256, 0, stream>>>(partial, finalv, nblk, nchunks);
    k_wm<<<16, 256, 0, stream>>>(finalv, finalv + 256, mean, wm, inv_n);
    k_whiten<<<2048, 256, 0, stream>>>(x, mean, wm, out, npos);
}

// Round 7
// 155.344 us; speedup vs baseline: 2.0677x; 1.5340x over previous
//
#include <hip/hip_runtime.h>

// Decorrelation (iterative whitening) normalization.
// Input:  (64, 56, 56, 256) f32, NHWC (C contiguous). N = 200704 positions.
// Groups: 16 groups x 16 channels. Newton-Schulz x5 for Sigma^{-1/2}.
//
// Lane mapping (streaming kernels): lane handles channels [4*lane, 4*lane+4)
// => quad (4 consecutive lanes) == one 16-channel group. Cross-channel products
// within the group use DPP quad_perm broadcasts (VALU, no LDS pipe).
//
// Round-7: rounds 3-6 fit dur = 90us(stream) + 17.4us x blocks/CU. The
// per-block cost is the LDS atomicAdd merge (68 atomic RMW instrs/thread,
// ~150cy each, serial on the LDS pipe). Replaced with a 3-barrier tree of
// plain ds_write_b128/ds_read_b128 through 2 LDS slots; wave 0 stores the
// block record. Cov record stored column-major (legal: cov is symmetric).
//
// ws float layout:
//   [0,    256)   : final channel sums (zeroed, k_reduce atomics)
//   [256,  4352)  : final cov sums
//   [4352, 4608)  : channel means (written by k_wm)
//   [4608, 8704)  : whitening matrices (g*256 + i*16 + j)
//   [8704, ...)   : per-block partials, nblk x 4352 (plain coalesced stores)

constexpr int CCH = 256;
constexpr float EPSV = 1e-3f;
constexpr int PSTRIDE = 4352;   // floats per partial record
constexpr int STATBLK = 1024;   // k_stats blocks (4 blocks/CU, 16 waves/CU)

// DPP quad_perm broadcast of lane (quad_base + S) within each 4-lane quad.
#define QB(S, comp) __int_as_float(__builtin_amdgcn_update_dpp( \
    0, __float_as_int(comp), (S) * 0x55, 0xF, 0xF, 1))

// c_{4S+t}.a += v.a * u_t  where u_t = QB(S, v component t).
#define FMA4(C, V, U) \
    { C.x += (V).x * (U); C.y += (V).y * (U); C.z += (V).z * (U); C.w += (V).w * (U); }

#define QUAD(S, CA, CB, CC, CD, V)                                        \
    {                                                                     \
        const float u0 = QB(S, (V).x), u1 = QB(S, (V).y),                 \
                    u2 = QB(S, (V).z), u3 = QB(S, (V).w);                 \
        FMA4(CA, V, u0) FMA4(CB, V, u1) FMA4(CC, V, u2) FMA4(CD, V, u3)   \
    }

#define ACCPOS(V)                                                         \
    {                                                                     \
        ss.x += (V).x; ss.y += (V).y; ss.z += (V).z; ss.w += (V).w;       \
        QUAD(0, c0, c1, c2, c3, V)                                        \
        QUAD(1, c4, c5, c6, c7, V)                                        \
        QUAD(2, c8, c9, c10, c11, V)                                      \
        QUAD(3, c12, c13, c14, c15, V)                                    \
    }

// LDS slot layout: cov[g][j][i] at g*260 + j*16 + i (group stride 260 floats
// = 1040B => 16B bank stagger per group, <=2-way conflicts); sums at
// 4160 + lane*4. Slot size 4416 floats.
constexpr int SLOTF = 4416;

#define SLOT_WRITE(S)                                                       \
    {                                                                       \
        *reinterpret_cast<float4*>(&sl[S][4160 + lane * 4]) = ss;           \
        float* cb = &sl[S][g * 260 + i0];                                   \
        *reinterpret_cast<float4*>(cb + 0 * 16)  = c0;                      \
        *reinterpret_cast<float4*>(cb + 1 * 16)  = c1;                      \
        *reinterpret_cast<float4*>(cb + 2 * 16)  = c2;                      \
        *reinterpret_cast<float4*>(cb + 3 * 16)  = c3;                      \
        *reinterpret_cast<float4*>(cb + 4 * 16)  = c4;                      \
        *reinterpret_cast<float4*>(cb + 5 * 16)  = c5;                      \
        *reinterpret_cast<float4*>(cb + 6 * 16)  = c6;                      \
        *reinterpret_cast<float4*>(cb + 7 * 16)  = c7;                      \
        *reinterpret_cast<float4*>(cb + 8 * 16)  = c8;                      \
        *reinterpret_cast<float4*>(cb + 9 * 16)  = c9;                      \
        *reinterpret_cast<float4*>(cb + 10 * 16) = c10;                     \
        *reinterpret_cast<float4*>(cb + 11 * 16) = c11;                     \
        *reinterpret_cast<float4*>(cb + 12 * 16) = c12;                     \
        *reinterpret_cast<float4*>(cb + 13 * 16) = c13;                     \
        *reinterpret_cast<float4*>(cb + 14 * 16) = c14;                     \
        *reinterpret_cast<float4*>(cb + 15 * 16) = c15;                     \
    }

#define ADD4(C, P)                                                          \
    {                                                                       \
        const float4 t_ = *reinterpret_cast<const float4*>(P);              \
        C.x += t_.x; C.y += t_.y; C.z += t_.z; C.w += t_.w;                 \
    }

#define SLOT_ADD(S)                                                         \
    {                                                                       \
        ADD4(ss, &sl[S][4160 + lane * 4]);                                  \
        const float* cb = &sl[S][g * 260 + i0];                             \
        ADD4(c0,  cb + 0 * 16)  ADD4(c1,  cb + 1 * 16)                      \
        ADD4(c2,  cb + 2 * 16)  ADD4(c3,  cb + 3 * 16)                      \
        ADD4(c4,  cb + 4 * 16)  ADD4(c5,  cb + 5 * 16)                      \
        ADD4(c6,  cb + 6 * 16)  ADD4(c7,  cb + 7 * 16)                      \
        ADD4(c8,  cb + 8 * 16)  ADD4(c9,  cb + 9 * 16)                      \
        ADD4(c10, cb + 10 * 16) ADD4(c11, cb + 11 * 16)                     \
        ADD4(c12, cb + 12 * 16) ADD4(c13, cb + 13 * 16)                     \
        ADD4(c14, cb + 14 * 16) ADD4(c15, cb + 15 * 16)                     \
    }

__global__ __launch_bounds__(256, 4) void k_stats(const float* __restrict__ x,
                                                  float* __restrict__ partial,
                                                  int npos2) {
    const int tid = threadIdx.x;
    const int lane = tid & 63;
    const int w = tid >> 6;
    const int wave = blockIdx.x * 4 + w;
    const int nw = gridDim.x * 4;
    const int g = lane >> 2;
    const int i0 = (lane & 3) * 4;

    float4 ss = {0.f, 0.f, 0.f, 0.f};
    float4 c0 = ss, c1 = ss, c2 = ss, c3 = ss, c4 = ss, c5 = ss, c6 = ss,
           c7 = ss, c8 = ss, c9 = ss, c10 = ss, c11 = ss, c12 = ss, c13 = ss,
           c14 = ss, c15 = ss;

    const float* bx = x + lane * 4;

    // Stream position PAIRS (2KB contiguous per wave-iter, 2 loads in flight).
    int q = wave;
    if (q < npos2) {
        float4 va = *reinterpret_cast<const float4*>(bx + (size_t)(2 * q) * CCH);
        float4 vb = *reinterpret_cast<const float4*>(bx + (size_t)(2 * q + 1) * CCH);
        while (true) {
            const int qn = q + nw;
            const bool more = qn < npos2;
            float4 vna = va, vnb = vb;
            if (more) {
                vna = *reinterpret_cast<const float4*>(bx + (size_t)(2 * qn) * CCH);
                vnb = *reinterpret_cast<const float4*>(bx + (size_t)(2 * qn + 1) * CCH);
            }
            ACCPOS(va);
            ACCPOS(vb);
            if (!more) break;
            q = qn;
            va = vna;
            vb = vnb;
        }
    }

    // Block merge: plain-store tree through 2 LDS slots (NO atomics).
    __shared__ float sl[2][SLOTF];

    if (w == 1) SLOT_WRITE(0);
    if (w == 3) SLOT_WRITE(1);
    __syncthreads();
    if (w == 0) SLOT_ADD(0);
    if (w == 2) SLOT_ADD(1);
    __syncthreads();
    if (w == 2) SLOT_WRITE(0);
    __syncthreads();
    if (w == 0) {
        SLOT_ADD(0);
        // Wave 0 stores the block record. Cov stored COLUMN-major
        // (rec[256 + g*256 + j*16 + i]) -- legal since cov is symmetric;
        // k_reduce is element-wise and k_wm is transpose-invariant.
        float* rec = partial + (size_t)blockIdx.x * PSTRIDE;
        *reinterpret_cast<float4*>(&rec[lane * 4]) = ss;
        float* cb = &rec[256 + g * 256 + i0];
        *reinterpret_cast<float4*>(cb + 0 * 16)  = c0;
        *reinterpret_cast<float4*>(cb + 1 * 16)  = c1;
        *reinterpret_cast<float4*>(cb + 2 * 16)  = c2;
        *reinterpret_cast<float4*>(cb + 3 * 16)  = c3;
        *reinterpret_cast<float4*>(cb + 4 * 16)  = c4;
        *reinterpret_cast<float4*>(cb + 5 * 16)  = c5;
        *reinterpret_cast<float4*>(cb + 6 * 16)  = c6;
        *reinterpret_cast<float4*>(cb + 7 * 16)  = c7;
        *reinterpret_cast<float4*>(cb + 8 * 16)  = c8;
        *reinterpret_cast<float4*>(cb + 9 * 16)  = c9;
        *reinterpret_cast<float4*>(cb + 10 * 16) = c10;
        *reinterpret_cast<float4*>(cb + 11 * 16) = c11;
        *reinterpret_cast<float4*>(cb + 12 * 16) = c12;
        *reinterpret_cast<float4*>(cb + 13 * 16) = c13;
        *reinterpret_cast<float4*>(cb + 14 * 16) = c14;
        *reinterpret_cast<float4*>(cb + 15 * 16) = c15;
    }
}

// Reduce nblk partial records into the final 4352 accumulators.
__global__ __launch_bounds__(256) void k_reduce(const float* __restrict__ partial,
                                                float* __restrict__ finalv,
                                                int nblk, int nchunks) {
    const int t = blockIdx.x * blockDim.x + threadIdx.x;
    const int total = nchunks * PSTRIDE;
    if (t >= total) return;
    const int chunk = t / PSTRIDE;
    const int e = t - chunk * PSTRIDE;
    const int r0 = chunk * 64;
    const int rend = (r0 + 64 < nblk) ? r0 + 64 : nblk;
    const float* src = partial + (size_t)r0 * PSTRIDE + e;
    float acc = 0.f;
    for (int r = r0; r < rend; ++r, src += PSTRIDE) acc += *src;
    atomicAdd(&finalv[e], acc);
}

// One block per group; thread (i,j) owns element (i,j) of the 16x16 matrices.
__global__ __launch_bounds__(256) void k_wm(const float* __restrict__ sums,
                                            const float* __restrict__ covs,
                                            float* __restrict__ mean,
                                            float* __restrict__ wm,
                                            float inv_n) {
    const int g = blockIdx.x;
    const int tid = threadIdx.x;
    const int i = tid >> 4;
    const int j = tid & 15;

    __shared__ float mu[16];
    __shared__ float sig[16][17];
    __shared__ float P[16][17];
    __shared__ float T[16][17];
    __shared__ float U[16][17];

    if (tid < 16) {
        float m = sums[g * 16 + tid] * inv_n;
        mu[tid] = m;
        mean[g * 16 + tid] = m;
    }
    __syncthreads();

    const float cov = covs[(g * 16 + i) * 16 + j] * inv_n - mu[i] * mu[j];
    const float s = (1.0f - EPSV) * cov + ((i == j) ? EPSV : 0.0f);
    sig[i][j] = s;
    __syncthreads();

    float tr = 0.f;
#pragma unroll
    for (int k = 0; k < 16; ++k) tr += sig[k][k];
    __syncthreads();

    sig[i][j] = s / tr;               // sigma_n
    P[i][j] = (i == j) ? 1.0f : 0.0f;
    __syncthreads();

    for (int it = 0; it < 5; ++it) {
        float a = 0.f;
#pragma unroll
        for (int k = 0; k < 16; ++k) a += P[i][k] * P[k][j];
        T[i][j] = a;
        __syncthreads();

        float b = 0.f;
#pragma unroll
        for (int k = 0; k < 16; ++k) b += T[i][k] * P[k][j];
        U[i][j] = b;
        __syncthreads();

        float c = 0.f;
#pragma unroll
        for (int k = 0; k < 16; ++k) c += U[i][k] * sig[k][j];
        const float pn = 1.5f * P[i][j] - 0.5f * c;
        __syncthreads();
        P[i][j] = pn;
        __syncthreads();
    }

    wm[(g * 16 + i) * 16 + j] = P[i][j] * rsqrtf(tr);
}

__global__ __launch_bounds__(256) void k_whiten(const float* __restrict__ x,
                                                const float* __restrict__ mean,
                                                const float* __restrict__ wm,
                                                float* __restrict__ out,
                                                int npos) {
    const int tid = threadIdx.x;
    const int lane = tid & 63;
    const int wave = blockIdx.x * (blockDim.x >> 6) + (tid >> 6);
    const int nwaves = gridDim.x * (blockDim.x >> 6);
    const int g = lane >> 2;
    const int i0 = (lane & 3) * 4;

    // Per-lane whitening rows: 4 output channels x 16 input channels.
    float w[4][16];
    const float* wg = wm + g * 256;
#pragma unroll
    for (int a = 0; a < 4; ++a)
#pragma unroll
        for (int j = 0; j < 16; ++j) w[a][j] = wg[(i0 + a) * 16 + j];

    const float4 mu4 = *reinterpret_cast<const float4*>(mean + lane * 4);
    const float* bx = x + lane * 4;
    float* bo = out + lane * 4;

    int p = wave;
    if (p >= npos) return;
    float4 v = *reinterpret_cast<const float4*>(bx + (size_t)p * CCH);
    while (true) {
        const int pn = p + nwaves;
        const bool more = pn < npos;
        float4 vn = v;
        if (more) vn = *reinterpret_cast<const float4*>(bx + (size_t)pn * CCH);

        v.x -= mu4.x; v.y -= mu4.y; v.z -= mu4.z; v.w -= mu4.w;
        float acc[4] = {0.f, 0.f, 0.f, 0.f};
#define WSTEP(S)                                                         \
        {                                                                \
            const float u0 = QB(S, v.x), u1 = QB(S, v.y),                \
                        u2 = QB(S, v.z), u3 = QB(S, v.w);                \
            _Pragma("unroll")                                            \
            for (int a = 0; a < 4; ++a) {                                \
                acc[a] += w[a][(S) * 4 + 0] * u0 + w[a][(S) * 4 + 1] * u1 \
                        + w[a][(S) * 4 + 2] * u2 + w[a][(S) * 4 + 3] * u3; \
            }                                                            \
        }
        WSTEP(0) WSTEP(1) WSTEP(2) WSTEP(3)
#undef WSTEP
        float4 o;
        o.x = acc[0]; o.y = acc[1]; o.z = acc[2]; o.w = acc[3];
        *reinterpret_cast<float4*>(bo + (size_t)p * CCH) = o;

        if (!more) break;
        p = pn;
        v = vn;
    }
}

extern "C" void kernel_launch(void* const* d_in, const int* in_sizes, int n_in,
                              void* d_out, int out_size, void* d_ws, size_t ws_size,
                              hipStream_t stream) {
    const float* x = (const float*)d_in[0];
    float* out = (float*)d_out;
    float* ws = (float*)d_ws;

    const int total = in_sizes[0];
    const int npos = total / CCH;   // 200704
    const float inv_n = 1.0f / (float)npos;

    float* finalv = ws;            // [0,4352): sums+covs
    float* mean = ws + 4352;
    float* wm = ws + 4608;
    float* partial = ws + 8704;    // nblk * PSTRIDE floats

    long avail = (long)(ws_size / 4) - 8704;
    int nblk = (int)(avail / PSTRIDE);
    if (nblk > STATBLK) nblk = STATBLK;
    if (nblk < 64) nblk = 64;   // ws is always big enough for this in practice

    // zero only the final accumulators (k_reduce atomics land here)
    hipMemsetAsync(d_ws, 0, 4352 * sizeof(float), stream);

    k_stats<<<nblk, 256, 0, stream>>>(x, partial, npos / 2);
    const int nchunks = (nblk + 63) / 64;
    const int rthreads = nchunks * PSTRIDE;
    k_reduce<<<(rthreads + 255) / 256, 256, 0, stream>>>(partial, finalv, nblk, nchunks);
    k_wm<<<16, 256, 0, stream>>>(finalv, finalv + 256, mean, wm, inv_n);
    k_whiten<<<2048, 256, 0, stream>>>(x, mean, wm, out, npos);
}